// Round 1
// baseline (83.535 us; speedup 1.0000x reference)
//
#include <hip/hip_runtime.h>

#define NN 8192
#define BB 1024
#define KK 8
#define CC 10
#define NT 256
#define CHUNK (NN/NT)   // 32

__global__ void pack_kernel(const int* __restrict__ c_in, uint2* __restrict__ packed) {
    int n = blockIdx.x * blockDim.x + threadIdx.x;
    if (n >= NN) return;
    const int4* p = reinterpret_cast<const int4*>(c_in + (size_t)n * KK);
    int4 lo4 = p[0], hi4 = p[1];
    unsigned lo = (unsigned)(0*CC + lo4.x) | ((unsigned)(1*CC + lo4.y) << 8)
                | ((unsigned)(2*CC + lo4.z) << 16) | ((unsigned)(3*CC + lo4.w) << 24);
    unsigned hi = (unsigned)(4*CC + hi4.x) | ((unsigned)(5*CC + hi4.y) << 8)
                | ((unsigned)(6*CC + hi4.z) << 16) | ((unsigned)(7*CC + hi4.w) << 24);
    packed[n] = make_uint2(lo, hi);
}

__device__ __forceinline__ void scan256(float* scr, int t) {
    // Hillis-Steele inclusive scan over NT entries
    for (int d = 1; d < NT; d <<= 1) {
        float v = scr[t];
        float add = (t >= d) ? scr[t - d] : 0.0f;
        __syncthreads();
        scr[t] = v + add;
        __syncthreads();
    }
}

__global__ __launch_bounds__(NT) void beran_kernel(
    const float* __restrict__ c_p, const float* __restrict__ bandwidth,
    const int* __restrict__ c_in, const int* __restrict__ delta_in,
    const uint2* __restrict__ packed, float* __restrict__ out)
{
    __shared__ float a[NN];          // 32 KB row buffer (weights -> cumsum -> fxi-cumsum -> surv -> steps)
    __shared__ float ttab[KK * CC];  // per-block metric table
    __shared__ float scratch[NT];
    __shared__ unsigned dmask[NT];   // delta bitmask, word t covers n in [32t, 32t+32)
    __shared__ float sA;

    const int b = blockIdx.x;
    const int t = threadIdx.x;
    const int base = t * CHUNK;

    // ---- delta bitmask (32 bits per thread, chunk-aligned) ----
    {
        const int4* dp4 = reinterpret_cast<const int4*>(delta_in + base);
        unsigned m = 0;
        #pragma unroll
        for (int i = 0; i < 8; i++) {
            int4 v = dp4[i];
            m |= ((unsigned)(v.x & 1) << (4*i))
               | ((unsigned)(v.y & 1) << (4*i + 1))
               | ((unsigned)(v.z & 1) << (4*i + 2))
               | ((unsigned)(v.w & 1) << (4*i + 3));
        }
        dmask[t] = m;
    }

    // ---- softmax + metric table t[k][c] = invbw - 2*p*invbw ; A = sum p^2*invbw ----
    if (t < KK) {
        const int k = t;
        float v[CC];
        float mx = -1e30f;
        #pragma unroll
        for (int c = 0; c < CC; c++) { v[c] = c_p[((size_t)b*KK + k)*CC + c]; mx = fmaxf(mx, v[c]); }
        float se = 0.0f;
        #pragma unroll
        for (int c = 0; c < CC; c++) { v[c] = expf(v[c] - mx); se += v[c]; }
        float inv = 1.0f / se;
        float Ak = 0.0f;
        #pragma unroll
        for (int c = 0; c < CC; c++) {
            float p  = v[c] * inv;
            float bw = bandwidth[k*CC + c];
            bw = fminf(fmaxf(bw, 0.001f), 10.0f);
            float ib = 1.0f / bw;
            ttab[k*CC + c] = ib - 2.0f * p * ib;
            Ak += p * p * ib;
        }
        scratch[t] = Ak;
    }
    __syncthreads();
    if (t == 0) { float A = 0.0f; for (int k = 0; k < KK; k++) A += scratch[k]; sA = A; }
    __syncthreads();
    const float A = sA;

    // ---- weights: w[n] = exp(-(A + sum_k t[k][c_in[n,k]])) ----
    float lsum = 0.0f;
    if (packed) {
        for (int n = t; n < NN; n += NT) {
            uint2 pk = packed[n];
            float m = A;
            unsigned lo = pk.x, hi = pk.y;
            #pragma unroll
            for (int k = 0; k < 4; k++) m += ttab[(lo >> (8*k)) & 0xff];
            #pragma unroll
            for (int k = 0; k < 4; k++) m += ttab[(hi >> (8*k)) & 0xff];
            float w = expf(-m);
            a[n] = w;
            lsum += w;
        }
    } else {
        for (int n = t; n < NN; n += NT) {
            const int4* p4 = reinterpret_cast<const int4*>(c_in + (size_t)n * KK);
            int4 lo4 = p4[0], hi4 = p4[1];
            float m = A;
            m += ttab[0*CC + lo4.x] + ttab[1*CC + lo4.y] + ttab[2*CC + lo4.z] + ttab[3*CC + lo4.w];
            m += ttab[4*CC + hi4.x] + ttab[5*CC + hi4.y] + ttab[6*CC + hi4.z] + ttab[7*CC + hi4.w];
            float w = expf(-m);
            a[n] = w;
            lsum += w;
        }
    }
    scratch[t] = lsum;
    __syncthreads();
    for (int sd = NT/2; sd > 0; sd >>= 1) {
        if (t < sd) scratch[t] += scratch[t + sd];
        __syncthreads();
    }
    const float s = scratch[0];
    __syncthreads();
    const float invs = (s < 1e-13f) ? 0.0f : 1.0f / s;

    // ---- scan 1: inclusive cumsum of W = w*invs ----
    float run = 0.0f;
    #pragma unroll
    for (int i = 0; i < CHUNK; i++) { run += a[base + i] * invs; a[base + i] = run; }
    scratch[t] = run;
    __syncthreads();
    scan256(scratch, t);
    {
        const float off = (t == 0) ? 0.0f : scratch[t - 1];
        __syncthreads();   // protect scratch reuse + establish a[] chunk sums before boundary reads
        #pragma unroll
        for (int i = 0; i < CHUNK; i++) a[base + i] += off;
    }
    __syncthreads();

    // ---- xi pass: xi = log(1-cs[n-1]) - log(1-cs[n]) with isclose-to-1 zeroing;
    //      fxi = delta * xi ; chunk-local inclusive cumsum of fxi written in place ----
    const float ISO = 1.001e-5f;  // atol + rtol*|1| = 1e-8 + 1e-5
    float csprev = (t == 0) ? 0.0f : a[base - 1];
    __syncthreads();               // boundary reads before overwrite
    {
        const unsigned dm = dmask[t];
        float run2 = 0.0f;
        #pragma unroll
        for (int i = 0; i < CHUNK; i++) {
            const float cs = a[base + i];
            const bool bad = (fabsf(csprev - 1.0f) <= ISO) || (fabsf(cs - 1.0f) <= ISO);
            float xi = bad ? 0.0f : (logf(1.0f - csprev) - logf(1.0f - cs));
            float f  = ((dm >> i) & 1u) ? xi : 0.0f;
            run2 += f;
            a[base + i] = run2;
            csprev = cs;
        }
        scratch[t] = run2;
    }
    __syncthreads();
    scan256(scratch, t);
    {
        const float off2 = (t == 0) ? 0.0f : scratch[t - 1];
        __syncthreads();
        #pragma unroll
        for (int i = 0; i < CHUNK; i++) {
            float hz = a[base + i] + off2;
            a[base + i] = expf(-hz);   // surv_func
        }
    }
    __syncthreads();

    // ---- write surv_func (coalesced), then steps in place ----
    float* outS = out + (size_t)b * NN;
    for (int n = t; n < NN; n += NT) outS[n] = a[n];
    float sprev = (t == 0) ? 1.0f : a[base - 1];   // steps[0] = 1 - surv[0]
    __syncthreads();               // boundary + coalesced reads done before overwrite
    float lss = 0.0f;
    #pragma unroll
    for (int i = 0; i < CHUNK; i++) {
        float sv = a[base + i];
        float st = sprev - sv;
        a[base + i] = st;
        lss += st;
        sprev = sv;
    }
    scratch[t] = lss;
    __syncthreads();
    for (int sd = NT/2; sd > 0; sd >>= 1) {
        if (t < sd) scratch[t] += scratch[t + sd];
        __syncthreads();
    }
    const float ss = scratch[0];
    __syncthreads();
    const float invss = (ss < 1e-13f) ? 0.0f : 1.0f / ss;
    float* outT = out + (size_t)BB * NN + (size_t)b * NN;
    for (int n = t; n < NN; n += NT) outT[n] = a[n] * invss;
}

extern "C" void kernel_launch(void* const* d_in, const int* in_sizes, int n_in,
                              void* d_out, int out_size, void* d_ws, size_t ws_size,
                              hipStream_t stream) {
    const float* c_p       = (const float*)d_in[0];
    const float* bandwidth = (const float*)d_in[1];
    const int*   c_in      = (const int*)d_in[2];
    const int*   delta_in  = (const int*)d_in[3];
    float* out = (float*)d_out;

    uint2* packed = nullptr;
    if (ws_size >= (size_t)NN * sizeof(uint2)) {
        packed = (uint2*)d_ws;
        pack_kernel<<<NN / NT, NT, 0, stream>>>(c_in, packed);
    }
    beran_kernel<<<BB, NT, 0, stream>>>(c_p, bandwidth, c_in, delta_in, packed, out);
}

// Round 2
// 33.734 us; speedup vs baseline: 2.4763x; 2.4763x over previous
//
#include <hip/hip_runtime.h>

#define NN 8192
#define BB 1024
#define KK 8
#define CC 10
#define NT 256
#define CHUNK (NN/NT)   // 32
#define NW (NT/64)      // 4 waves

// LDS row-buffer swizzle: rotate column by row index -> chunked (stride-32)
// accesses hit 32 distinct banks instead of 1. Strided accesses stay free.
__device__ __forceinline__ int swz(int n) {
    return (n & ~31) | ((n + (n >> 5)) & 31);
}

__global__ void pack_kernel(const int* __restrict__ c_in, const int* __restrict__ delta_in,
                            uint2* __restrict__ packed, unsigned* __restrict__ dmask_g) {
    int n = blockIdx.x * blockDim.x + threadIdx.x;
    if (n >= NN) return;
    const int4* p = reinterpret_cast<const int4*>(c_in + (size_t)n * KK);
    int4 lo4 = p[0], hi4 = p[1];
    unsigned lo = (unsigned)(0*CC + lo4.x) | ((unsigned)(1*CC + lo4.y) << 8)
                | ((unsigned)(2*CC + lo4.z) << 16) | ((unsigned)(3*CC + lo4.w) << 24);
    unsigned hi = (unsigned)(4*CC + hi4.x) | ((unsigned)(5*CC + hi4.y) << 8)
                | ((unsigned)(6*CC + hi4.z) << 16) | ((unsigned)(7*CC + hi4.w) << 24);
    packed[n] = make_uint2(lo, hi);
    // delta bitmask: word w covers n in [32w, 32w+32)
    unsigned long long bal = __ballot(delta_in[n] & 1);
    if ((threadIdx.x & 63) == 0) {
        dmask_g[n >> 5]       = (unsigned)(bal & 0xffffffffull);
        dmask_g[(n >> 5) + 1] = (unsigned)(bal >> 32);
    }
}

// exclusive scan of v over the 256 threads; ws must be a fresh float[NW] slot
__device__ __forceinline__ float block_excl_scan(float v, int lane, int wv, float* ws) {
    float x = v;
    #pragma unroll
    for (int d = 1; d < 64; d <<= 1) {
        float y = __shfl_up(x, d);
        if (lane >= d) x += y;
    }
    if (lane == 63) ws[wv] = x;
    __syncthreads();
    float woff = 0.0f;
    #pragma unroll
    for (int w = 0; w < NW - 1; w++)
        if (w < wv) woff += ws[w];      // broadcast reads, conflict-free
    return woff + (x - v);
}

__global__ __launch_bounds__(NT) void beran_kernel(
    const float* __restrict__ c_p, const float* __restrict__ bandwidth,
    const int* __restrict__ c_in, const int* __restrict__ delta_in,
    const uint2* __restrict__ packed, const unsigned* __restrict__ dmask_g,
    float* __restrict__ out)
{
    __shared__ float a[NN];          // 32 KB swizzled row buffer
    __shared__ float ttab[KK * CC];
    __shared__ float Apart[KK];
    __shared__ float wsumS[NW];      // reduction slot (weight sum)
    __shared__ float wsumB[NW];      // scan slot (cumsum offsets)
    __shared__ float wsumC[NW];      // scan slot (hazard offsets)
    __shared__ unsigned dmls[NT];    // fallback delta masks

    const int b    = blockIdx.x;
    const int t    = threadIdx.x;
    const int lane = t & 63;
    const int wv   = t >> 6;
    const int base = t * CHUNK;

    // ---- softmax + metric table t[k][c] = invbw - 2*p*invbw ; A = sum p^2*invbw ----
    if (t < KK) {
        const int k = t;
        float v[CC];
        float mx = -1e30f;
        #pragma unroll
        for (int c = 0; c < CC; c++) { v[c] = c_p[((size_t)b*KK + k)*CC + c]; mx = fmaxf(mx, v[c]); }
        float se = 0.0f;
        #pragma unroll
        for (int c = 0; c < CC; c++) { v[c] = __expf(v[c] - mx); se += v[c]; }
        float inv = 1.0f / se;
        float Ak = 0.0f;
        #pragma unroll
        for (int c = 0; c < CC; c++) {
            float p  = v[c] * inv;
            float bw = bandwidth[k*CC + c];
            bw = fminf(fmaxf(bw, 0.001f), 10.0f);
            float ib = 1.0f / bw;
            ttab[k*CC + c] = ib - 2.0f * p * ib;
            Ak += p * p * ib;
        }
        Apart[k] = Ak;
    }
    __syncthreads();
    float A = 0.0f;
    #pragma unroll
    for (int k = 0; k < KK; k++) A += Apart[k];   // broadcast reads

    // ---- pass A (strided): w[n] = exp(-(A + sum_k ttab[c_in[n,k]])) -> a[] ----
    float lsum = 0.0f;
    unsigned dm;
    if (packed) {
        dm = dmask_g[t];
        for (int j = 0; j < CHUNK; j++) {
            int n = j * NT + t;
            uint2 pk = packed[n];
            float m = A;
            #pragma unroll
            for (int k = 0; k < 4; k++) m += ttab[(pk.x >> (8*k)) & 0xff];
            #pragma unroll
            for (int k = 0; k < 4; k++) m += ttab[(pk.y >> (8*k)) & 0xff];
            float w = __expf(-m);
            a[swz(n)] = w;
            lsum += w;
        }
    } else {
        for (int j = 0; j < CHUNK; j++) {
            int n = j * NT + t;
            unsigned long long bal = __ballot(delta_in[n] & 1);
            if (lane == 0) {
                dmls[(n >> 5)]     = (unsigned)(bal & 0xffffffffull);
                dmls[(n >> 5) + 1] = (unsigned)(bal >> 32);
            }
            const int4* p4 = reinterpret_cast<const int4*>(c_in + (size_t)n * KK);
            int4 lo4 = p4[0], hi4 = p4[1];
            float m = A;
            m += ttab[0*CC + lo4.x] + ttab[1*CC + lo4.y] + ttab[2*CC + lo4.z] + ttab[3*CC + lo4.w];
            m += ttab[4*CC + hi4.x] + ttab[5*CC + hi4.y] + ttab[6*CC + hi4.z] + ttab[7*CC + hi4.w];
            float w = __expf(-m);
            a[swz(n)] = w;
            lsum += w;
        }
    }

    // ---- weight-sum reduction (shuffle) ----
    float ws = lsum;
    #pragma unroll
    for (int d = 32; d; d >>= 1) ws += __shfl_xor(ws, d);
    if (lane == 0) wsumS[wv] = ws;
    __syncthreads();                 // also makes all a[] writes visible
    float s = wsumS[0] + wsumS[1] + wsumS[2] + wsumS[3];
    const float invs = (s < 1e-13f) ? 0.0f : 1.0f / s;
    if (!packed) dm = dmls[t];

    // ---- pass B (chunked): raw cumsum into registers ----
    float creg[CHUNK];
    float run = 0.0f;
    #pragma unroll
    for (int i = 0; i < CHUNK; i++) { run += a[swz(base + i)]; creg[i] = run; }
    const float off_raw = block_excl_scan(run, lane, wv, wsumB);

    // ---- pass C (registers): xi + hazard cumsum ----
    const float ISO = 1.00001e-5f;   // atol + rtol*|1|
    float csprev = off_raw * invs;   // t==0 -> 0
    float run2 = 0.0f;
    #pragma unroll
    for (int i = 0; i < CHUNK; i++) {
        float cs = (creg[i] + off_raw) * invs;
        bool bad = (fabsf(csprev - 1.0f) <= ISO) || (fabsf(cs - 1.0f) <= ISO);
        float xi = bad ? 0.0f : (__logf(1.0f - csprev) - __logf(1.0f - cs));
        float f  = ((dm >> i) & 1u) ? xi : 0.0f;
        run2 += f;
        creg[i] = run2;
        csprev = cs;
    }
    const float off2 = block_excl_scan(run2, lane, wv, wsumC);

    // ---- pass D (chunked write): surv_func into a[] ----
    #pragma unroll
    for (int i = 0; i < CHUNK; i++) a[swz(base + i)] = __expf(-(creg[i] + off2));
    __syncthreads();

    // ---- pass E (strided float4): write surv_func and normalized steps ----
    const float surv_last = a[swz(NN - 1)];          // broadcast
    const float ss = 1.0f - surv_last;               // telescoped step sum
    const float invss = (ss < 1e-13f) ? 0.0f : 1.0f / ss;
    float* outS = out + (size_t)b * NN;
    float* outT = out + (size_t)BB * NN + (size_t)b * NN;
    #pragma unroll
    for (int j = 0; j < NN / (NT * 4); j++) {        // 8 iterations
        int n0 = j * NT * 4 + t * 4;
        float s0 = a[swz(n0)];
        float s1 = a[swz(n0 + 1)];
        float s2 = a[swz(n0 + 2)];
        float s3 = a[swz(n0 + 3)];
        float sp = (n0 == 0) ? 1.0f : a[swz(n0 - 1)];
        float4 sv = make_float4(s0, s1, s2, s3);
        *reinterpret_cast<float4*>(outS + n0) = sv;
        float4 st = make_float4((sp - s0) * invss, (s0 - s1) * invss,
                                (s1 - s2) * invss, (s2 - s3) * invss);
        *reinterpret_cast<float4*>(outT + n0) = st;
    }
}

extern "C" void kernel_launch(void* const* d_in, const int* in_sizes, int n_in,
                              void* d_out, int out_size, void* d_ws, size_t ws_size,
                              hipStream_t stream) {
    const float* c_p       = (const float*)d_in[0];
    const float* bandwidth = (const float*)d_in[1];
    const int*   c_in      = (const int*)d_in[2];
    const int*   delta_in  = (const int*)d_in[3];
    float* out = (float*)d_out;

    uint2*    packed  = nullptr;
    unsigned* dmask_g = nullptr;
    const size_t need = (size_t)NN * sizeof(uint2) + (size_t)(NN / 32) * sizeof(unsigned);
    if (ws_size >= need) {
        packed  = (uint2*)d_ws;
        dmask_g = (unsigned*)((char*)d_ws + (size_t)NN * sizeof(uint2));
        pack_kernel<<<NN / NT, NT, 0, stream>>>(c_in, delta_in, packed, dmask_g);
    }
    beran_kernel<<<BB, NT, 0, stream>>>(c_p, bandwidth, c_in, delta_in, packed, dmask_g, out);
}

// Round 3
// 30.225 us; speedup vs baseline: 2.7637x; 1.1161x over previous
//
#include <hip/hip_runtime.h>

#define NN 8192
#define BB 1024
#define KK 8
#define CC 10
#define NT 512
#define CHUNK (NN/NT)   // 16
#define NW (NT/64)      // 8 waves

// LDS row-buffer swizzle: rotate column by row index -> chunked (stride-16/32)
// accesses spread across banks (<=2-way, free per m136). Strided stays free.
__device__ __forceinline__ int swz(int n) {
    return (n & ~31) | ((n + (n >> 5)) & 31);
}

__global__ void pack_kernel(const int* __restrict__ c_in, const int* __restrict__ delta_in,
                            unsigned* __restrict__ pairs, unsigned* __restrict__ dmask_g) {
    int n = blockIdx.x * blockDim.x + threadIdx.x;
    if (n >= NN) return;
    const int4* p = reinterpret_cast<const int4*>(c_in + (size_t)n * KK);
    int4 lo = p[0], hi = p[1];
    unsigned p0 = (unsigned)(lo.x * 10 + lo.y);   // pair index 0..99
    unsigned p1 = (unsigned)(lo.z * 10 + lo.w);
    unsigned p2 = (unsigned)(hi.x * 10 + hi.y);
    unsigned p3 = (unsigned)(hi.z * 10 + hi.w);
    pairs[n] = p0 | (p1 << 7) | (p2 << 14) | (p3 << 21);
    // delta bitmask: word w covers n in [32w, 32w+32)
    unsigned long long bal = __ballot(delta_in[n] & 1);
    if ((threadIdx.x & 63) == 0) {
        dmask_g[n >> 5]       = (unsigned)(bal & 0xffffffffull);
        dmask_g[(n >> 5) + 1] = (unsigned)(bal >> 32);
    }
}

// exclusive scan of v over NT threads; ws must be a fresh float[NW] slot
__device__ __forceinline__ float block_excl_scan(float v, int lane, int wv, float* ws) {
    float x = v;
    #pragma unroll
    for (int d = 1; d < 64; d <<= 1) {
        float y = __shfl_up(x, d);
        if (lane >= d) x += y;
    }
    if (lane == 63) ws[wv] = x;
    __syncthreads();
    float woff = 0.0f;
    #pragma unroll
    for (int w = 0; w < NW - 1; w++)
        if (w < wv) woff += ws[w];      // broadcast reads, conflict-free
    return woff + (x - v);
}

__global__ __launch_bounds__(NT, 8) void beran_kernel(
    const float* __restrict__ c_p, const float* __restrict__ bandwidth,
    const int* __restrict__ c_in, const int* __restrict__ delta_in,
    const unsigned* __restrict__ pairs, const unsigned* __restrict__ dmask_g,
    float* __restrict__ out)
{
    __shared__ float a[NN];             // 32 KB swizzled row buffer
    __shared__ float ttab[KK * CC];     // single-concept table
    __shared__ float ttab2[4 * 100];    // pair table: ttab2[k*100 + c0*10+c1]
    __shared__ float Apart[KK];
    __shared__ float wsumS[NW];
    __shared__ float wsumB[NW];
    __shared__ float wsumC[NW];
    __shared__ unsigned dmls[NN / 32];  // fallback delta masks

    const int b    = blockIdx.x;
    const int t    = threadIdx.x;
    const int lane = t & 63;
    const int wv   = t >> 6;
    const int base = t * CHUNK;

    // ---- softmax + metric table t[k][c] = invbw - 2*p*invbw ; A = sum p^2*invbw ----
    if (t < KK) {
        const int k = t;
        float v[CC];
        float mx = -1e30f;
        #pragma unroll
        for (int c = 0; c < CC; c++) { v[c] = c_p[((size_t)b*KK + k)*CC + c]; mx = fmaxf(mx, v[c]); }
        float se = 0.0f;
        #pragma unroll
        for (int c = 0; c < CC; c++) { v[c] = __expf(v[c] - mx); se += v[c]; }
        float inv = 1.0f / se;
        float Ak = 0.0f;
        #pragma unroll
        for (int c = 0; c < CC; c++) {
            float p  = v[c] * inv;
            float bw = bandwidth[k*CC + c];
            bw = fminf(fmaxf(bw, 0.001f), 10.0f);
            float ib = 1.0f / bw;
            ttab[k*CC + c] = ib - 2.0f * p * ib;
            Ak += p * p * ib;
        }
        Apart[k] = Ak;
    }
    __syncthreads();
    // build pair table + broadcast A
    if (t < 400) {
        int k = t / 100, p = t % 100;
        ttab2[t] = ttab[(k*2)*CC + p/10] + ttab[(k*2+1)*CC + p%10];
    }
    float A = 0.0f;
    #pragma unroll
    for (int k = 0; k < KK; k++) A += Apart[k];   // broadcast reads
    __syncthreads();

    // ---- pass A (strided): w[n] = exp(-(A + sum of 4 pair-table gathers)) -> a[] ----
    float lsum = 0.0f;
    unsigned dm;
    if (pairs) {
        for (int j = 0; j < CHUNK; j++) {
            int n = j * NT + t;
            unsigned pk = pairs[n];
            float m = A;
            m += ttab2[pk & 127];
            m += ttab2[100 + ((pk >> 7) & 127)];
            m += ttab2[200 + ((pk >> 14) & 127)];
            m += ttab2[300 + (pk >> 21)];
            float w = __expf(-m);
            a[swz(n)] = w;
            lsum += w;
        }
    } else {
        for (int j = 0; j < CHUNK; j++) {
            int n = j * NT + t;
            unsigned long long bal = __ballot(delta_in[n] & 1);
            if (lane == 0) {
                dmls[(n >> 5)]     = (unsigned)(bal & 0xffffffffull);
                dmls[(n >> 5) + 1] = (unsigned)(bal >> 32);
            }
            const int4* p4 = reinterpret_cast<const int4*>(c_in + (size_t)n * KK);
            int4 lo4 = p4[0], hi4 = p4[1];
            float m = A;
            m += ttab[0*CC + lo4.x] + ttab[1*CC + lo4.y] + ttab[2*CC + lo4.z] + ttab[3*CC + lo4.w];
            m += ttab[4*CC + hi4.x] + ttab[5*CC + hi4.y] + ttab[6*CC + hi4.z] + ttab[7*CC + hi4.w];
            float w = __expf(-m);
            a[swz(n)] = w;
            lsum += w;
        }
    }

    // ---- weight-sum reduction (shuffle) ----
    float wsr = lsum;
    #pragma unroll
    for (int d = 32; d; d >>= 1) wsr += __shfl_xor(wsr, d);
    if (lane == 0) wsumS[wv] = wsr;
    __syncthreads();                 // also makes a[] writes + dmls visible
    float s = 0.0f;
    #pragma unroll
    for (int w = 0; w < NW; w++) s += wsumS[w];
    const float invs = (s < 1e-13f) ? 0.0f : 1.0f / s;
    {
        unsigned dm32 = pairs ? dmask_g[t >> 1] : dmls[t >> 1];
        dm = (dm32 >> ((t & 1) * 16)) & 0xffffu;
    }

    // ---- pass B (chunked): raw cumsum into registers ----
    float creg[CHUNK];
    float run = 0.0f;
    #pragma unroll
    for (int i = 0; i < CHUNK; i++) { run += a[swz(base + i)]; creg[i] = run; }
    const float off_raw = block_excl_scan(run, lane, wv, wsumB);

    // ---- pass C (registers): xi + hazard cumsum, one log per element ----
    const float ISO = 1.00001e-5f;   // atol + rtol*|1|
    float csprev = off_raw * invs;   // t==0 -> 0
    float Lprev  = __logf(1.0f - csprev);   // t==0 -> 0
    float run2 = 0.0f;
    #pragma unroll
    for (int i = 0; i < CHUNK; i++) {
        float cs = (creg[i] + off_raw) * invs;
        float L  = __logf(1.0f - cs);
        bool bad = (fabsf(csprev - 1.0f) <= ISO) || (fabsf(cs - 1.0f) <= ISO);
        float xi = bad ? 0.0f : (Lprev - L);
        float f  = ((dm >> i) & 1u) ? xi : 0.0f;
        run2 += f;
        creg[i] = run2;
        csprev = cs;
        Lprev  = L;
    }
    const float off2 = block_excl_scan(run2, lane, wv, wsumC);

    // ---- pass D (chunked write): surv_func into a[] ----
    #pragma unroll
    for (int i = 0; i < CHUNK; i++) a[swz(base + i)] = __expf(-(creg[i] + off2));
    __syncthreads();

    // ---- pass E (strided float4): write surv_func and normalized steps ----
    const float surv_last = a[swz(NN - 1)];          // broadcast
    const float ss = 1.0f - surv_last;               // telescoped step sum
    const float invss = (ss < 1e-13f) ? 0.0f : 1.0f / ss;
    float* outS = out + (size_t)b * NN;
    float* outT = out + (size_t)BB * NN + (size_t)b * NN;
    #pragma unroll
    for (int j = 0; j < NN / (NT * 4); j++) {        // 4 iterations
        int n0 = j * NT * 4 + t * 4;
        float s0 = a[swz(n0)];
        float s1 = a[swz(n0 + 1)];
        float s2 = a[swz(n0 + 2)];
        float s3 = a[swz(n0 + 3)];
        float sp = (n0 == 0) ? 1.0f : a[swz(n0 - 1)];
        float4 sv = make_float4(s0, s1, s2, s3);
        *reinterpret_cast<float4*>(outS + n0) = sv;
        float4 st = make_float4((sp - s0) * invss, (s0 - s1) * invss,
                                (s1 - s2) * invss, (s2 - s3) * invss);
        *reinterpret_cast<float4*>(outT + n0) = st;
    }
}

extern "C" void kernel_launch(void* const* d_in, const int* in_sizes, int n_in,
                              void* d_out, int out_size, void* d_ws, size_t ws_size,
                              hipStream_t stream) {
    const float* c_p       = (const float*)d_in[0];
    const float* bandwidth = (const float*)d_in[1];
    const int*   c_in      = (const int*)d_in[2];
    const int*   delta_in  = (const int*)d_in[3];
    float* out = (float*)d_out;

    unsigned* pairs   = nullptr;
    unsigned* dmask_g = nullptr;
    const size_t need = (size_t)NN * sizeof(unsigned) + (size_t)(NN / 32) * sizeof(unsigned);
    if (ws_size >= need) {
        pairs   = (unsigned*)d_ws;
        dmask_g = (unsigned*)((char*)d_ws + (size_t)NN * sizeof(unsigned));
        pack_kernel<<<NN / 256, 256, 0, stream>>>(c_in, delta_in, pairs, dmask_g);
    }
    beran_kernel<<<BB, NT, 0, stream>>>(c_p, bandwidth, c_in, delta_in, pairs, dmask_g, out);
}